// Round 10
// baseline (11089.865 us; speedup 1.0000x reference)
//
#include <hip/hip_runtime.h>
#include <cstdint>
#include <cstddef>

// CIN: B=1024, M=40, D=64, HK=128. rows = B*D (row = b*64 + d)
// y[r,h] = sum_i x0[r,i] * ( sum_j xk[r,j] * W[i,j,h] )
// ROUND 9 (resubmit): mfma_f32_32x32x16_bf16 (halves B/A bytes per FLOP vs
// 16x16x32 -- r6 vs r8 isolated B-traffic-per-FLOP as the stall driver).
// xk hi/lo bf16 planes in LDS (split once/layer); x0 applied per K=16 chunk
// in exact f32 (each chunk lies within one i, so t is transient).
// 3-term split: xk*w ~= xkh*wh + xkh*wl + xkl*wh  (error ~2^-18 rel)

typedef __attribute__((ext_vector_type(4)))  float f4v;
typedef __attribute__((ext_vector_type(16))) float f16v;
typedef __attribute__((ext_vector_type(8)))  short s8v;

__device__ __forceinline__ unsigned short f2bf(float f){
  unsigned u = __float_as_uint(f);
  u += 0x7fffu + ((u >> 16) & 1u);      // RNE on bf16 boundary
  return (unsigned short)(u >> 16);
}

// ---------------- weight prep: split + transpose into ws ----------------
// ws layout (ushort units) -- unchanged since round 2 (validated):
//  W0hi @ 0        [128][2560]   (k = i*64 + j, j<40 real else 0)
//  W0lo @ 327680
//  W1hi @ 655360   [128][5120]   (k = i*128 + j)
//  W1lo @ 1310720
//  W2hi @ 1966080
//  W2lo @ 2621440            total 3,276,800 ushorts = 6.55 MB
__global__ void prep_weights(const float* __restrict__ W0,
                             const float* __restrict__ W1,
                             const float* __restrict__ W2,
                             unsigned short* __restrict__ ws)
{
  const int total = 327680 + 655360 + 655360;
  for (int e = blockIdx.x * blockDim.x + threadIdx.x; e < total;
       e += gridDim.x * blockDim.x){
    float w; int hi, lo;
    if (e < 327680){
      int h = e / 2560, k = e % 2560;
      int i = k >> 6, j = k & 63;
      w = (j < 40) ? W0[(i*40 + j)*128 + h] : 0.f;   // W0[i][j][h]
      hi = e; lo = 327680 + e;
    } else if (e < 983040){
      int r = e - 327680;
      int h = r / 5120, k = r % 5120;
      w = W1[k*128 + h];
      hi = 655360 + r; lo = 1310720 + r;
    } else {
      int r = e - 983040;
      int h = r / 5120, k = r % 5120;
      w = W2[k*128 + h];
      hi = 1966080 + r; lo = 2621440 + r;
    }
    unsigned short hb = f2bf(w);
    float whf = __uint_as_float((unsigned)hb << 16);
    unsigned short lb = f2bf(w - whf);
    ws[hi] = hb; ws[lo] = lb;
  }
}

// ---------------- main fused kernel ----------------
// block: 512 threads = 8 waves; 256 rows (4 b * 64 d); wave tile 64r x 64c
// as 2x2 of 32x32 MFMA tiles (mt = row tile, nt = col tile).
//   cgi = wv&1 (col half), rgi = wv>>1 (batch index within block)
// LDS: hi plane @0, lo plane @32768 (ushort units), [256][128] bf16 each,
//   swizzled: idx = row*128 + (col ^ ((row&7)<<3)).  Total 128 KiB, 1 block/CU.
// 32x32x16 layouts: A/B: lane l -> row/col = l&31, k = (l>>5)*8 + e
//                   C/D: col = l&31, row = (reg&3) + 8*(reg>>2) + 4*(l>>5)

template<int J, int KT, bool WB>
__device__ __forceinline__ void run_layer(
    const unsigned short* __restrict__ Whi,   // lo plane at +128*KT
    const float* __restrict__ xg,
    unsigned short* xkU, float* __restrict__ out,
    int layerOff, int blockRow, int tid)
{
  constexpr int NKB = J / 16;                 // K=16 chunks per i
  constexpr size_t WLO = (size_t)128 * KT;
  const int lane = tid & 63;
  const int wv   = tid >> 6;
  const int cgi  = wv & 1, rgi = wv >> 1;
  const int lc   = lane & 31, hl = lane >> 5;
  const int b    = (blockRow >> 6) + rgi;     // this wave's batch

  f16v y[2][2];
#pragma unroll
  for (int a = 0; a < 2; a++)
#pragma unroll
    for (int c = 0; c < 2; c++)
#pragma unroll
      for (int r = 0; r < 16; r++)
        y[a][c][r] = 0.f;

  const unsigned short* wp[2];
#pragma unroll
  for (int nt = 0; nt < 2; nt++)
    wp[nt] = Whi + (size_t)(cgi*64 + nt*32 + lc) * KT + hl*8;

  const float* xrow = xg + (size_t)b * 40 * 64;     // x[b][i][d]
  f16v zero16;
#pragma unroll
  for (int r = 0; r < 16; r++) zero16[r] = 0.f;

#pragma unroll 1
  for (int i = 0; i < 40; i++){
    // x0 for this wave's C-rows: d = mt*32 + g*8 + hl*4 + c
    f4v x0s[2][4];
#pragma unroll
    for (int mt = 0; mt < 2; mt++)
#pragma unroll
      for (int g = 0; g < 4; g++)
        x0s[mt][g] = *(const f4v*)(xrow + i*64 + mt*32 + g*8 + hl*4);

#pragma unroll
    for (int kc = 0; kc < NKB; kc++){
      const int k0 = (i*NKB + kc) * 16;       // ushort offset into W row
      s8v bh[2], bl[2];
#pragma unroll
      for (int nt = 0; nt < 2; nt++){
        bh[nt] = *(const s8v*)(wp[nt] + k0);
        bl[nt] = *(const s8v*)(wp[nt] + WLO + k0);
      }
      const int jbase = kc*16 + hl*8;         // j of this lane's A k-slice
#pragma unroll
      for (int mt = 0; mt < 2; mt++){
        const int row = rgi*64 + mt*32 + lc;
        const int ci  = row*128 + (jbase ^ ((row & 7) << 3));
        const s8v ah = *(const s8v*)(xkU + ci);
        const s8v al = *(const s8v*)(xkU + 32768 + ci);
#pragma unroll
        for (int nt = 0; nt < 2; nt++){
          f16v t = __builtin_amdgcn_mfma_f32_32x32x16_bf16(ah, bh[nt], zero16, 0, 0, 0);
          t = __builtin_amdgcn_mfma_f32_32x32x16_bf16(ah, bl[nt], t, 0, 0, 0);
          t = __builtin_amdgcn_mfma_f32_32x32x16_bf16(al, bh[nt], t, 0, 0, 0);
#pragma unroll
          for (int r = 0; r < 16; r++)
            y[mt][nt][r] += x0s[mt][r >> 2][r & 3] * t[r];   // exact f32
        }
      }
    }
  }

  // ---- pool over d from registers: wave owns b=rgi slice, cols cgi*64+nt*32+lc
  float ps[2];
#pragma unroll
  for (int nt = 0; nt < 2; nt++){
    float ssum = 0.f;
#pragma unroll
    for (int mt = 0; mt < 2; mt++)
#pragma unroll
      for (int r = 0; r < 16; r++)
        ssum += y[mt][nt][r];
    ssum += __shfl_xor(ssum, 32);             // combine hl halves (row 4-blocks)
    ps[nt] = ssum;
  }
  if (hl == 0){
#pragma unroll
    for (int nt = 0; nt < 2; nt++)
      out[(size_t)b*384 + layerOff + cgi*64 + nt*32 + lc] = ps[nt];
  }

  if (WB){
    __syncthreads();            // all waves done READING old planes
    // write y as new xk hi/lo planes (C/D layout above)
#pragma unroll
    for (int mt = 0; mt < 2; mt++){
#pragma unroll
      for (int nt = 0; nt < 2; nt++){
        const int col = cgi*64 + nt*32 + lc;
#pragma unroll
        for (int r = 0; r < 16; r++){
          const int row = rgi*64 + mt*32 + (r & 3) + 8*(r >> 2) + 4*hl;
          const float v = y[mt][nt][r];
          unsigned short hb = f2bf(v);
          unsigned short lb = f2bf(v - __uint_as_float((unsigned)hb << 16));
          const int pi = row*128 + (col ^ ((row & 7) << 3));
          xkU[pi] = hb;
          xkU[32768 + pi] = lb;
        }
      }
    }
    __syncthreads();            // new planes visible
  }
}

__global__ __launch_bounds__(512, 2) void cin_main(
    const float* __restrict__ xg,
    const unsigned short* __restrict__ wsbase,
    float* __restrict__ out)
{
  extern __shared__ unsigned short xkU[];   // 2 planes x [256][128] bf16 = 128 KiB
  const int tid = threadIdx.x;
  const int blockRow = blockIdx.x * 256;

  // stage layer-1 xk = x (cols j<40 real, pad to 64; cols 64..127 unused in L1)
#pragma unroll 1
  for (int it = 0; it < 32; it++){
    int idx = it*512 + tid;
    int row = idx & 255, j = idx >> 8;      // j in [0,64)
    float v = 0.f;
    if (j < 40){
      int bb = (blockRow >> 6) + (row >> 6);
      v = xg[((size_t)bb*40 + j)*64 + (row & 63)];
    }
    unsigned short hb = f2bf(v);
    unsigned short lb = f2bf(v - __uint_as_float((unsigned)hb << 16));
    const int pi = row*128 + (j ^ ((row & 7) << 3));
    xkU[pi] = hb;
    xkU[32768 + pi] = lb;
  }
  __syncthreads();

  run_layer< 64, 2560, true >(wsbase,           xg, xkU, out,   0, blockRow, tid);
  run_layer<128, 5120, true >(wsbase + 655360,  xg, xkU, out, 128, blockRow, tid);
  run_layer<128, 5120, false>(wsbase + 1966080, xg, xkU, out, 256, blockRow, tid);
}

extern "C" void kernel_launch(void* const* d_in, const int* in_sizes, int n_in,
                              void* d_out, int out_size, void* d_ws, size_t ws_size,
                              hipStream_t stream)
{
  (void)in_sizes; (void)n_in; (void)out_size; (void)ws_size;
  const float* x  = (const float*)d_in[0];
  const float* W0 = (const float*)d_in[1];
  const float* W1 = (const float*)d_in[2];
  const float* W2 = (const float*)d_in[3];
  float* out = (float*)d_out;
  unsigned short* ws = (unsigned short*)d_ws;   // needs 6,553,600 bytes

  hipFuncSetAttribute((const void*)cin_main,
                      hipFuncAttributeMaxDynamicSharedMemorySize, 131072);

  prep_weights<<<2048, 256, 0, stream>>>(W0, W1, W2, ws);
  cin_main<<<256, 512, 131072, stream>>>(x, ws, out);
}